// Round 6
// baseline (121.082 us; speedup 1.0000x reference)
//
#include <hip/hip_runtime.h>
#include <math.h>

// MMD loss. Z = concat(X,Y) [8192 x 256] fp32.
// Round 14: R13 (counted vmcnt, 4-ring) only -3.9us; R11-R13 pipeline edits
//   each ~-3..6us => latency-COVER model wrong, not latency. Occupancy 12.5%
//   = ~4 waves/CU avg vs 8 configured: grid 512 = exactly 2 blocks/CU (zero
//   rotation; stalls uncovered) + 64.5KB LDS caps residency + 5-tile
//   stragglers. Fix: ring 4->3 bufs (48KB) -> 3 blocks/CU; grid 1040 x 2
//   tiles (2080 = 1040*2 exact, no stragglers; 1040 = 8*130 XCD-clean);
//   prefetch depth 2, steady vmcnt(4), vmcnt(0) only at final phase.
//   12 waves/CU + rotation. k_prep/k_bw byte-identical.
// Math (R5-R13 verified, absmax 0.0): 1-phase bf16 Gram, sq exact fp32;
//   d2 = sq_i + sq_j - 2 z_i.z_j; bandwidth analytic
//   (sum d2 = 2M*S - 2||sum z||^2); K = t+t^2+t^4+t^8+t^16, t=exp(-d2/(4bw));
//   out = (Sxx + Syy - Sxy_both)/n^2, fp64 accumulation.

#define N_HALF 4096
#define DIM 256
#define M_TOT 8192
#define TILE 128
#define NT 64
#define NT_HALF 32
#define NCHUNK 1040  // blocks; 2 tiles each: 2080 flat-triangle tiles exactly

typedef unsigned short ushort_t;
typedef __attribute__((ext_vector_type(8))) short short8;   // 8 bf16 = 4 VGPRs
typedef __attribute__((ext_vector_type(4))) float floatx4;  // MFMA C/D

// Fragment-swizzled bf16 Z (4 MB). For row-block rb (16 rows) and k-chunk kk
// (32 k): g_zf[rb*4096 + kk*512 + q*128 + m*8 + j] = Z[rb*16+m][kk*32+q*8+j].
// The 16B unit of lane (quad=q, l15=m) sits at byte lane*16 within the 1KB
// chunk: MFMA frag ds_read_b128 is linear in lane -> conflict-free; staging
// global_load_lds (dest base+lane*16, src +lane*16) is a pure linear copy.
__device__ ushort_t g_zf[M_TOT * DIM];

__device__ __forceinline__ ushort_t f2bf(float f) {  // RNE, finite inputs
    unsigned u = __float_as_uint(f);
    u += 0x7fffu + ((u >> 16) & 1u);
    return (ushort_t)(u >> 16);
}

__device__ __forceinline__ void gload_lds16(const ushort_t* g, ushort_t* l) {
    __builtin_amdgcn_global_load_lds(
        (const __attribute__((address_space(1))) void*)g,
        (__attribute__((address_space(3))) void*)l, 16, 0, 0);
}

// Stage one kk-slice (A 8KB + B 8KB) into one ring buffer.
// Wave w stages chunks {2w, 2w+1} of A and B: 4 gload_lds of 1KB per wave.
__device__ __forceinline__ void stage1(const ushort_t* gA, const ushort_t* gB,
                                       int kk, ushort_t* buf, int wave, int lane) {
#pragma unroll
    for (int i = 0; i < 2; ++i) {
        const int c = wave * 2 + i;
        gload_lds16(gA + (size_t)c * 4096 + kk * 512 + lane * 8, buf + c * 512);
        gload_lds16(gB + (size_t)c * 4096 + kk * 512 + lane * 8, buf + 4096 + c * 512);
    }
}

// ---------------- k_prep: convert(swizzled) + row norms + col sums -----------
// 512 blocks x 256 threads; wave w owns 4 rows; lane l owns cols [4l,4l+4).
__global__ __launch_bounds__(256) void k_prep(const float* __restrict__ X,
                                              const float* __restrict__ Y,
                                              float* __restrict__ sq,
                                              float* __restrict__ colsum_r,
                                              float* __restrict__ Ssum_r) {
    __shared__ float cpart[4][256];
    __shared__ float spart[4];
    const int t = threadIdx.x, wave = t >> 6, lane = t & 63;
    const int row0 = blockIdx.x * 16 + wave * 4;
    // swizzle coords for this lane's 4 columns [4l, 4l+4)
    const int kk = lane >> 3, q = (lane >> 1) & 3, j0 = (lane & 1) * 4;
    float c0 = 0.f, c1 = 0.f, c2 = 0.f, c3 = 0.f, ssum = 0.f;
#pragma unroll
    for (int i = 0; i < 4; ++i) {
        const int row = row0 + i;
        const float* p = (row < N_HALF) ? (X + (size_t)row * DIM)
                                        : (Y + (size_t)(row - N_HALF) * DIM);
        const float4 v = *((const float4*)p + lane);
        ushort4 hi;
        hi.x = f2bf(v.x); hi.y = f2bf(v.y); hi.z = f2bf(v.z); hi.w = f2bf(v.w);
        const int rb = row >> 4, m = row & 15;
        *(ushort4*)(g_zf + (size_t)rb * 4096 + kk * 512 + q * 128 + m * 8 + j0) = hi;
        c0 += v.x; c1 += v.y; c2 += v.z; c3 += v.w;
        float s = fmaf(v.x, v.x, fmaf(v.y, v.y, fmaf(v.z, v.z, v.w * v.w)));
#pragma unroll
        for (int off = 32; off > 0; off >>= 1) s += __shfl_xor(s, off);
        if (lane == 0) sq[row] = s;
        ssum += s;  // butterfly left full sum in every lane
    }
    float4 cp; cp.x = c0; cp.y = c1; cp.z = c2; cp.w = c3;
    *(float4*)&cpart[wave][lane * 4] = cp;
    if (lane == 0) spart[wave] = ssum;
    __syncthreads();
    const float cs = cpart[0][t] + cpart[1][t] + cpart[2][t] + cpart[3][t];
    const int rep = blockIdx.x & 7;  // 8 replicas -> 64 adds/address
    atomicAdd(&colsum_r[rep * 256 + t], cs);  // poison -3e-13/rep: harmless
    if (t == 0) atomicAdd(&Ssum_r[rep], spart[0] + spart[1] + spart[2] + spart[3]);
}

// ---------------- k_bw: one block computes exp2 scale c2 once ----------------
// Same summation order as the old per-block prologue -> bit-identical c2.
__global__ __launch_bounds__(256) void k_bw(const float* __restrict__ colsum_r,
                                            const float* __restrict__ Ssum_r,
                                            float* __restrict__ c2out) {
    __shared__ double sred[4];
    const int t = threadIdx.x, lane = t & 63, wave = t >> 6;
    float csf = 0.f;
#pragma unroll
    for (int r = 0; r < 8; ++r) csf += colsum_r[r * 256 + t];
    double p = (double)csf * (double)csf;
#pragma unroll
    for (int off = 32; off > 0; off >>= 1) p += __shfl_xor(p, off);
    if (lane == 0) sred[wave] = p;
    __syncthreads();
    if (t == 0) {
        const double SS = sred[0] + sred[1] + sred[2] + sred[3];
        float Sf = 0.f;
#pragma unroll
        for (int r = 0; r < 8; ++r) Sf += Ssum_r[r];
        const double sum_d2 = 2.0 * (double)M_TOT * (double)Sf - 2.0 * SS;
        const double bw = sum_d2 / ((double)M_TOT * (double)M_TOT - (double)M_TOT);
        c2out[0] = (float)(1.4426950408889634 / (4.0 * bw));  // exp2 scale
    }
}

// ---------------- k_gram: counted-vmcnt 3-ring pipelined MFMA Gram -----------
// 1040 blocks x 256 threads; 2 tiles/block; 3x16KB LDS ring (48KB) -> 3
// blocks/CU resident (12 waves/CU) with rotation; prefetch depth 2.
__global__ __launch_bounds__(256, 3) void k_gram(const float* __restrict__ sq,
                                                 const float* __restrict__ c2p,
                                                 double* __restrict__ acc,
                                                 unsigned* __restrict__ cnt,
                                                 float* __restrict__ out) {
    // ring buf b: A slice [0,4096), B slice [4096,8192) ushorts (8 KB each).
    __shared__ __attribute__((aligned(16))) ushort_t lds[3][8192];
    __shared__ double redw[4][3];

    // XCD-band swizzle (1040 = 8*130): same-XCD blocks contiguous in triangle.
    const int bid = (int)blockIdx.x;
    const int cc = (bid & 7) * 130 + (bid >> 3);
    const int f0 = cc * 2;  // first flat tile index of this block (2 tiles)

    const int t = threadIdx.x;
    const int lane = t & 63, wave = t >> 6;
    const int l15 = lane & 15, quad = lane >> 4;
    const int wrow = (wave >> 1) * 64, wcol = (wave & 1) * 64;
    const int a0 = (wave >> 1) * 4, b0 = (wave & 1) * 4;  // frag chunk bases
    const int laneoff = quad * 128 + l15 * 8;  // = lane*16B: linear, no conflict

    const float c2 = c2p[0];  // wave-uniform scalar load
    const float twoc2 = 2.f * c2;

    // triangular decode of f0 -> (ti, tj), tj >= ti
    int ti = (int)((129.0f - sqrtf(16641.0f - 8.0f * (float)f0)) * 0.5f);
    if (ti < 0) ti = 0; if (ti > NT - 1) ti = NT - 1;
    while (ti * NT - ti * (ti - 1) / 2 > f0) --ti;
    while ((ti + 1) * NT - (ti + 1) * ti / 2 <= f0) ++ti;
    int tj = ti + (f0 - (ti * NT - ti * (ti - 1) / 2));

    // stage stream (runs 2 slices ahead of compute; 16 slices = 2 tiles)
    int s_ti = ti, s_tj = tj, s_kk = 0;
    const ushort_t* sgA = g_zf + (size_t)s_ti * 32768;
    const ushort_t* sgB = g_zf + (size_t)s_tj * 32768;
#define ADV_STAGE() do { if (++s_kk == 8) { s_kk = 0; ++s_tj;                 \
        if (s_tj == NT) { ++s_ti; s_tj = s_ti; }                              \
        sgA = g_zf + (size_t)s_ti * 32768;                                    \
        sgB = g_zf + (size_t)s_tj * 32768; } } while (0)

    // prime slices 0,1 into bufs 0,1 (8 loads in flight per wave)
#pragma unroll
    for (int p = 0; p < 2; ++p) {
        stage1(sgA, sgB, s_kk, lds[p], wave, lane);
        ADV_STAGE();
    }

    double lxx = 0.0, lxy = 0.0, lyy = 0.0;
    int pb = 0;  // ring buffer index of current compute slice

#pragma unroll 1
    for (int s = 0; s < 2; ++s) {
        floatx4 accv[4][4];
#pragma unroll
        for (int mi = 0; mi < 4; ++mi)
#pragma unroll
            for (int ni = 0; ni < 4; ++ni) accv[mi][ni] = (floatx4)0.f;

#pragma unroll
        for (int kkc = 0; kkc < 8; ++kkc) {
            // counted wait: current slice (4 loads/wave) complete once <=4
            // outstanding (in-order retire; the 1 newer slice = 4 loads).
            // Only the block's very last phase drains to 0.
            if (s == 1 && kkc == 7) asm volatile("s_waitcnt vmcnt(0)" ::: "memory");
            else                    asm volatile("s_waitcnt vmcnt(4)" ::: "memory");
            __builtin_amdgcn_s_barrier();
            __builtin_amdgcn_sched_barrier(0);

            const ushort_t* lA = lds[pb];
            const ushort_t* lB = lds[pb] + 4096;
            short8 af[4], bf[4];
#pragma unroll
            for (int mi = 0; mi < 4; ++mi)
                af[mi] = *(const short8*)(lA + (a0 + mi) * 512 + laneoff);
#pragma unroll
            for (int ni = 0; ni < 4; ++ni)
                bf[ni] = *(const short8*)(lB + (b0 + ni) * 512 + laneoff);

            // issue stage of slice p+2 into buf (pb+2)%3 (= buffer consumed at
            // phase p-1; all waves passed this phase's barrier after reading
            // it). No stage in the last two phases (slices exhausted).
            if (s == 0 || kkc < 6) {
                int sb = pb + 2; if (sb >= 3) sb -= 3;
                stage1(sgA, sgB, s_kk, lds[sb], wave, lane);
                ADV_STAGE();
            }
            if (++pb == 3) pb = 0;

            __builtin_amdgcn_s_setprio(1);
#pragma unroll
            for (int mi = 0; mi < 4; ++mi)
#pragma unroll
                for (int ni = 0; ni < 4; ++ni)
                    accv[mi][ni] = __builtin_amdgcn_mfma_f32_16x16x32_bf16(
                        af[mi], bf[ni], accv[mi][ni], 0, 0, 0);
            __builtin_amdgcn_s_setprio(0);
        }

        // ---- epilogue for (ti, tj). C/D: col = lane&15, row = quad*4+reg.
        // (slices of the next tile remain in flight under this epilogue)
        const int arow0 = ti * TILE, brow0 = tj * TILE;
        float nsj[4];
#pragma unroll
        for (int ni = 0; ni < 4; ++ni)
            nsj[ni] = -c2 * sq[brow0 + wcol + ni * 16 + l15];
        floatx4 nsi4[4];
#pragma unroll
        for (int mi = 0; mi < 4; ++mi) {
            const float4 sv = *(const float4*)&sq[arow0 + wrow + mi * 16 + quad * 4];
            nsi4[mi][0] = -c2 * sv.x; nsi4[mi][1] = -c2 * sv.y;
            nsi4[mi][2] = -c2 * sv.z; nsi4[mi][3] = -c2 * sv.w;
        }
        floatx4 sum4 = (floatx4)0.f;
#pragma unroll
        for (int mi = 0; mi < 4; ++mi) {
#pragma unroll
            for (int ni = 0; ni < 4; ++ni) {
                const floatx4 addv = nsi4[mi] + (floatx4)nsj[ni];
                floatx4 arg = twoc2 * accv[mi][ni] + addv;
                floatx4 tt;
#pragma unroll
                for (int r = 0; r < 4; ++r) tt[r] = exp2f(fminf(arg[r], 0.f));
                const floatx4 t2 = tt * tt, t4 = t2 * t2, t8 = t4 * t4, t16 = t8 * t8;
                sum4 += (tt + t2) + (t4 + t8) + t16;
            }
        }
        const float fsum = (sum4[0] + sum4[1]) + (sum4[2] + sum4[3]);
        const double contrib = ((ti == tj) ? 1.0 : 2.0) * (double)fsum;
        if (tj < NT_HALF)       lxx += contrib;   // block-uniform branches
        else if (ti < NT_HALF)  lxy += contrib;
        else                    lyy += contrib;

        // advance compute tile
        ++tj; if (tj == NT) { ++ti; tj = ti; }
    }
#undef ADV_STAGE

    // ---- block reduction + finalize ----
#pragma unroll
    for (int off = 32; off > 0; off >>= 1) {
        lxx += __shfl_xor(lxx, off);
        lxy += __shfl_xor(lxy, off);
        lyy += __shfl_xor(lyy, off);
    }
    if (lane == 0) { redw[wave][0] = lxx; redw[wave][1] = lxy; redw[wave][2] = lyy; }
    __syncthreads();
    if (t == 0) {
        double sxx = 0.0, sxy = 0.0, syy = 0.0;
#pragma unroll
        for (int wv = 0; wv < 4; ++wv) {
            sxx += redw[wv][0]; sxy += redw[wv][1]; syy += redw[wv][2];
        }
        if (sxx != 0.0) atomicAdd(&acc[0], sxx);
        if (sxy != 0.0) atomicAdd(&acc[1], sxy);
        if (syy != 0.0) atomicAdd(&acc[2], syy);
        __threadfence();  // release region adds before counter bump
        const unsigned old = atomicAdd(cnt, 1u);
        // counter starts at 0xAAAAAAAA (ws poison) or 0 — accept either
        if (old == (0xAAAAAAAAu + (unsigned)(NCHUNK - 1)) ||
            old == (unsigned)(NCHUNK - 1)) {
            const double xx = atomicAdd(&acc[0], 0.0);  // coherent reads
            const double xy = atomicAdd(&acc[1], 0.0);
            const double yy = atomicAdd(&acc[2], 0.0);
            out[0] = (float)((xx + yy - xy) *
                             (1.0 / ((double)N_HALF * (double)N_HALF)));
        }
    }
}

extern "C" void kernel_launch(void* const* d_in, const int* in_sizes, int n_in,
                              void* d_out, int out_size, void* d_ws, size_t ws_size,
                              hipStream_t stream) {
    const float* X = (const float*)d_in[0];
    const float* Y = (const float*)d_in[1];
    char* ws = (char*)d_ws;
    float* sq        = (float*)ws;               // 8192 f32  [0, 32768)
    float* colsum_r  = (float*)(ws + 32768);     // 8*256 f32 [32768, 40960)
    float* Ssum_r    = (float*)(ws + 40960);     // 8 f32     [40960, 40992)
    unsigned* cnt    = (unsigned*)(ws + 40992);  // 1 u32
    double* acc      = (double*)(ws + 41000);    // 3 f64 (8-aligned)
    float* c2ws      = (float*)(ws + 41024);     // 1 f32
    float* out = (float*)d_out;

    hipLaunchKernelGGL(k_prep, dim3(512), dim3(256), 0, stream,
                       X, Y, sq, colsum_r, Ssum_r);
    hipLaunchKernelGGL(k_bw, dim3(1), dim3(256), 0, stream,
                       colsum_r, Ssum_r, c2ws);
    hipLaunchKernelGGL(k_gram, dim3(NCHUNK), dim3(256), 0, stream,
                       sq, c2ws, acc, cnt, out);
}

// Round 7
// 115.803 us; speedup vs baseline: 1.0456x; 1.0456x over previous
//
#include <hip/hip_runtime.h>
#include <math.h>

// MMD loss. Z = concat(X,Y) [8192 x 256] fp32.
// Round 15: R14 (more blocks/occupancy) regressed 48.5->56.5: occupancy is
//   not the binder. Invariant across R11-R14: ~2K cyc per kk-slice at
//   constant 266 MB staged (A+B, 64KB/tile) ~= 5 TB/s effective gload_lds
//   -- staging bytes are the suspected binding resource (thin-K GEMM: 8 B
//   staged/output). Isolated change vs R13 (best, 48.5): A panel lives in
//   REGISTERS (32x short8 = 128 VGPR/wave, reused across the block's 4-tile
//   row-run, reloaded only on row-wrap); B keeps R13's counted-vmcnt 4-ring
//   (B-only: 2 gload_lds + 4 ds_read per phase, steady vmcnt(4), tail 2/0).
//   Staged bytes 266->133 MB (+33 MB plain A loads, once per block).
//   LDS 32KB; __launch_bounds__(256,2) = 256-VGPR budget (est ~245, no
//   spill; WRITE_SIZE is the spill canary). Grid/tail identical to R13.
// Math (R5-R14 verified, absmax 0.0): 1-phase bf16 Gram, sq exact fp32;
//   d2 = sq_i + sq_j - 2 z_i.z_j; bandwidth analytic
//   (sum d2 = 2M*S - 2||sum z||^2); K = t+t^2+t^4+t^8+t^16, t=exp(-d2/(4bw));
//   out = (Sxx + Syy - Sxy_both)/n^2, fp64 accumulation.

#define N_HALF 4096
#define DIM 256
#define M_TOT 8192
#define TILE 128
#define NT 64
#define NT_HALF 32
#define NCHUNK 512  // blocks; 480 do 4 tiles, 32 (cc%16==0) do 5: 2080 total

typedef unsigned short ushort_t;
typedef __attribute__((ext_vector_type(8))) short short8;   // 8 bf16 = 4 VGPRs
typedef __attribute__((ext_vector_type(4))) float floatx4;  // MFMA C/D

// Fragment-swizzled bf16 Z (4 MB). For row-block rb (16 rows) and k-chunk kk
// (32 k): g_zf[rb*4096 + kk*512 + q*128 + m*8 + j] = Z[rb*16+m][kk*32+q*8+j].
// The 16B unit of lane (quad=q, l15=m) sits at byte lane*16 within the 1KB
// chunk: MFMA frag reads (LDS or global) are linear in lane -> conflict-free
// b128 / fully-coalesced dwordx4; staging is a pure linear copy.
__device__ ushort_t g_zf[M_TOT * DIM];

__device__ __forceinline__ ushort_t f2bf(float f) {  // RNE, finite inputs
    unsigned u = __float_as_uint(f);
    u += 0x7fffu + ((u >> 16) & 1u);
    return (ushort_t)(u >> 16);
}

__device__ __forceinline__ void gload_lds16(const ushort_t* g, ushort_t* l) {
    __builtin_amdgcn_global_load_lds(
        (const __attribute__((address_space(1))) void*)g,
        (__attribute__((address_space(3))) void*)l, 16, 0, 0);
}

// Stage one B kk-slice (8 KB = 8 chunks of 1KB) into one ring buffer.
// Wave w stages chunks {2w, 2w+1}: 2 gload_lds of 1KB per wave.
__device__ __forceinline__ void stageB(const ushort_t* gB, int kk,
                                       ushort_t* buf, int wave, int lane) {
#pragma unroll
    for (int i = 0; i < 2; ++i) {
        const int c = wave * 2 + i;
        gload_lds16(gB + (size_t)c * 4096 + kk * 512 + lane * 8, buf + c * 512);
    }
}

// ---------------- k_prep: convert(swizzled) + row norms + col sums -----------
// 512 blocks x 256 threads; wave w owns 4 rows; lane l owns cols [4l,4l+4).
__global__ __launch_bounds__(256) void k_prep(const float* __restrict__ X,
                                              const float* __restrict__ Y,
                                              float* __restrict__ sq,
                                              float* __restrict__ colsum_r,
                                              float* __restrict__ Ssum_r) {
    __shared__ float cpart[4][256];
    __shared__ float spart[4];
    const int t = threadIdx.x, wave = t >> 6, lane = t & 63;
    const int row0 = blockIdx.x * 16 + wave * 4;
    // swizzle coords for this lane's 4 columns [4l, 4l+4)
    const int kk = lane >> 3, q = (lane >> 1) & 3, j0 = (lane & 1) * 4;
    float c0 = 0.f, c1 = 0.f, c2 = 0.f, c3 = 0.f, ssum = 0.f;
#pragma unroll
    for (int i = 0; i < 4; ++i) {
        const int row = row0 + i;
        const float* p = (row < N_HALF) ? (X + (size_t)row * DIM)
                                        : (Y + (size_t)(row - N_HALF) * DIM);
        const float4 v = *((const float4*)p + lane);
        ushort4 hi;
        hi.x = f2bf(v.x); hi.y = f2bf(v.y); hi.z = f2bf(v.z); hi.w = f2bf(v.w);
        const int rb = row >> 4, m = row & 15;
        *(ushort4*)(g_zf + (size_t)rb * 4096 + kk * 512 + q * 128 + m * 8 + j0) = hi;
        c0 += v.x; c1 += v.y; c2 += v.z; c3 += v.w;
        float s = fmaf(v.x, v.x, fmaf(v.y, v.y, fmaf(v.z, v.z, v.w * v.w)));
#pragma unroll
        for (int off = 32; off > 0; off >>= 1) s += __shfl_xor(s, off);
        if (lane == 0) sq[row] = s;
        ssum += s;  // butterfly left full sum in every lane
    }
    float4 cp; cp.x = c0; cp.y = c1; cp.z = c2; cp.w = c3;
    *(float4*)&cpart[wave][lane * 4] = cp;
    if (lane == 0) spart[wave] = ssum;
    __syncthreads();
    const float cs = cpart[0][t] + cpart[1][t] + cpart[2][t] + cpart[3][t];
    const int rep = blockIdx.x & 7;  // 8 replicas -> 64 adds/address
    atomicAdd(&colsum_r[rep * 256 + t], cs);  // poison -3e-13/rep: harmless
    if (t == 0) atomicAdd(&Ssum_r[rep], spart[0] + spart[1] + spart[2] + spart[3]);
}

// ---------------- k_bw: one block computes exp2 scale c2 once ----------------
// Same summation order as the old per-block prologue -> bit-identical c2.
__global__ __launch_bounds__(256) void k_bw(const float* __restrict__ colsum_r,
                                            const float* __restrict__ Ssum_r,
                                            float* __restrict__ c2out) {
    __shared__ double sred[4];
    const int t = threadIdx.x, lane = t & 63, wave = t >> 6;
    float csf = 0.f;
#pragma unroll
    for (int r = 0; r < 8; ++r) csf += colsum_r[r * 256 + t];
    double p = (double)csf * (double)csf;
#pragma unroll
    for (int off = 32; off > 0; off >>= 1) p += __shfl_xor(p, off);
    if (lane == 0) sred[wave] = p;
    __syncthreads();
    if (t == 0) {
        const double SS = sred[0] + sred[1] + sred[2] + sred[3];
        float Sf = 0.f;
#pragma unroll
        for (int r = 0; r < 8; ++r) Sf += Ssum_r[r];
        const double sum_d2 = 2.0 * (double)M_TOT * (double)Sf - 2.0 * SS;
        const double bw = sum_d2 / ((double)M_TOT * (double)M_TOT - (double)M_TOT);
        c2out[0] = (float)(1.4426950408889634 / (4.0 * bw));  // exp2 scale
    }
}

// ---------------- k_gram: A-in-registers + counted-vmcnt B ring --------------
// 512 blocks x 256 threads = 2 blocks/CU (VGPR-capped); 4x8KB B ring (32KB).
__global__ __launch_bounds__(256, 2) void k_gram(const float* __restrict__ sq,
                                                 const float* __restrict__ c2p,
                                                 double* __restrict__ acc,
                                                 unsigned* __restrict__ cnt,
                                                 float* __restrict__ out) {
    __shared__ __attribute__((aligned(16))) ushort_t lds[4][4096];  // B ring
    __shared__ double redw[4][3];

    // XCD-band swizzle (512 = 8*64): same-XCD blocks contiguous in triangle.
    const int bid = (int)blockIdx.x;
    const int cc = (bid & 7) * 64 + (bid >> 3);
    // 32 long blocks (cc%16==0 -> 4 per XCD) do 5 tiles; rest do 4.
    const int nst = ((cc & 15) == 0) ? 5 : 4;
    const int f0 = cc * 4 + ((cc + 15) >> 4);  // first flat tile of this block

    const int t = threadIdx.x;
    const int lane = t & 63, wave = t >> 6;
    const int l15 = lane & 15, quad = lane >> 4;
    const int wrow = (wave >> 1) * 64, wcol = (wave & 1) * 64;
    const int b0 = (wave & 1) * 4;             // B frag chunk base
    const int laneoff = quad * 128 + l15 * 8;  // = lane*16B: linear

    const float c2 = c2p[0];  // wave-uniform scalar load
    const float twoc2 = 2.f * c2;

    // triangular decode of f0 -> (ti, tj), tj >= ti
    int ti = (int)((129.0f - sqrtf(16641.0f - 8.0f * (float)f0)) * 0.5f);
    if (ti < 0) ti = 0; if (ti > NT - 1) ti = NT - 1;
    while (ti * NT - ti * (ti - 1) / 2 > f0) --ti;
    while ((ti + 1) * NT - (ti + 1) * ti / 2 <= f0) ++ti;
    int tj = ti + (f0 - (ti * NT - ti * (ti - 1) / 2));

    // ---- A panel (this wave's 64 rows x K=256) resident in registers ----
    short8 aR[4][8];  // 128 VGPR; [mi][kk], all indices static
    {
        const ushort_t* aBase =
            g_zf + (size_t)(ti * 8 + (wave >> 1) * 4) * 4096 + laneoff;
#pragma unroll
        for (int mi = 0; mi < 4; ++mi)
#pragma unroll
            for (int kk = 0; kk < 8; ++kk)
                aR[mi][kk] = *(const short8*)(aBase + (size_t)mi * 4096 + kk * 512);
    }

    // B stage stream (runs 3 slices ahead of compute)
    int s_ti = ti, s_tj = tj, s_kk = 0;
    const ushort_t* sgB = g_zf + (size_t)s_tj * 32768;
#define ADV_STAGE() do { if (++s_kk == 8) { s_kk = 0; ++s_tj;                 \
        if (s_tj == NT) { ++s_ti; s_tj = s_ti; }                              \
        sgB = g_zf + (size_t)s_tj * 32768; } } while (0)

    // prime B slices 0,1,2 into bufs 0,1,2 (6 loads in flight per wave)
#pragma unroll
    for (int p = 0; p < 3; ++p) {
        stageB(sgB, s_kk, lds[p], wave, lane);
        ADV_STAGE();
    }

    double lxx = 0.0, lxy = 0.0, lyy = 0.0;

#pragma unroll 1
    for (int s = 0; s < nst; ++s) {
        const bool last = (s == nst - 1);

        floatx4 accv[4][4];
#pragma unroll
        for (int mi = 0; mi < 4; ++mi)
#pragma unroll
            for (int ni = 0; ni < 4; ++ni) accv[mi][ni] = (floatx4)0.f;

#pragma unroll
        for (int kkc = 0; kkc < 8; ++kkc) {
            // counted wait: slice g (2 loads/wave) retired once <=4 outstanding
            // (in-order retire; 2 newer slices = 4 loads). Tail: 2 then 0.
            if (last && kkc == 6)      asm volatile("s_waitcnt vmcnt(2)" ::: "memory");
            else if (last && kkc == 7) asm volatile("s_waitcnt vmcnt(0)" ::: "memory");
            else                       asm volatile("s_waitcnt vmcnt(4)" ::: "memory");
            __builtin_amdgcn_s_barrier();
            __builtin_amdgcn_sched_barrier(0);

            const ushort_t* lB = lds[kkc & 3];  // slice g=8s+kkc -> buf g&3
            short8 bf[4];
#pragma unroll
            for (int ni = 0; ni < 4; ++ni)
                bf[ni] = *(const short8*)(lB + (b0 + ni) * 512 + laneoff);

            // issue stage of slice g+3 into buf (g+3)&3 (consumed at phase
            // g-1; all waves passed this phase's barrier after reading it)
            if (!last || kkc < 5) {
                stageB(sgB, s_kk, lds[(kkc + 3) & 3], wave, lane);
                ADV_STAGE();
            }

            __builtin_amdgcn_s_setprio(1);
#pragma unroll
            for (int mi = 0; mi < 4; ++mi)
#pragma unroll
                for (int ni = 0; ni < 4; ++ni)
                    accv[mi][ni] = __builtin_amdgcn_mfma_f32_16x16x32_bf16(
                        aR[mi][kkc], bf[ni], accv[mi][ni], 0, 0, 0);
            __builtin_amdgcn_s_setprio(0);
        }

        // ---- epilogue for (ti, tj). C/D: col = lane&15, row = quad*4+reg.
        const int arow0 = ti * TILE, brow0 = tj * TILE;
        float nsj[4];
#pragma unroll
        for (int ni = 0; ni < 4; ++ni)
            nsj[ni] = -c2 * sq[brow0 + wcol + ni * 16 + l15];
        floatx4 nsi4[4];
#pragma unroll
        for (int mi = 0; mi < 4; ++mi) {
            const float4 sv = *(const float4*)&sq[arow0 + wrow + mi * 16 + quad * 4];
            nsi4[mi][0] = -c2 * sv.x; nsi4[mi][1] = -c2 * sv.y;
            nsi4[mi][2] = -c2 * sv.z; nsi4[mi][3] = -c2 * sv.w;
        }
        floatx4 sum4 = (floatx4)0.f;
#pragma unroll
        for (int mi = 0; mi < 4; ++mi) {
#pragma unroll
            for (int ni = 0; ni < 4; ++ni) {
                const floatx4 addv = nsi4[mi] + (floatx4)nsj[ni];
                floatx4 arg = twoc2 * accv[mi][ni] + addv;
                floatx4 tt;
#pragma unroll
                for (int r = 0; r < 4; ++r) tt[r] = exp2f(fminf(arg[r], 0.f));
                const floatx4 t2 = tt * tt, t4 = t2 * t2, t8 = t4 * t4, t16 = t8 * t8;
                sum4 += (tt + t2) + (t4 + t8) + t16;
            }
        }
        const float fsum = (sum4[0] + sum4[1]) + (sum4[2] + sum4[3]);
        const double contrib = ((ti == tj) ? 1.0 : 2.0) * (double)fsum;
        if (tj < NT_HALF)       lxx += contrib;   // block-uniform branches
        else if (ti < NT_HALF)  lxy += contrib;
        else                    lyy += contrib;

        // advance compute tile; reload A regs only on row wrap (rare)
        const int pti = ti;
        ++tj; if (tj == NT) { ++ti; tj = ti; }
        if (!last && ti != pti) {
            const ushort_t* aBase =
                g_zf + (size_t)(ti * 8 + (wave >> 1) * 4) * 4096 + laneoff;
#pragma unroll
            for (int mi = 0; mi < 4; ++mi)
#pragma unroll
                for (int kk = 0; kk < 8; ++kk)
                    aR[mi][kk] = *(const short8*)(aBase + (size_t)mi * 4096 + kk * 512);
        }
    }
#undef ADV_STAGE

    // ---- block reduction + finalize ----
#pragma unroll
    for (int off = 32; off > 0; off >>= 1) {
        lxx += __shfl_xor(lxx, off);
        lxy += __shfl_xor(lxy, off);
        lyy += __shfl_xor(lyy, off);
    }
    if (lane == 0) { redw[wave][0] = lxx; redw[wave][1] = lxy; redw[wave][2] = lyy; }
    __syncthreads();
    if (t == 0) {
        double sxx = 0.0, sxy = 0.0, syy = 0.0;
#pragma unroll
        for (int wv = 0; wv < 4; ++wv) {
            sxx += redw[wv][0]; sxy += redw[wv][1]; syy += redw[wv][2];
        }
        if (sxx != 0.0) atomicAdd(&acc[0], sxx);
        if (sxy != 0.0) atomicAdd(&acc[1], sxy);
        if (syy != 0.0) atomicAdd(&acc[2], syy);
        __threadfence();  // release region adds before counter bump
        const unsigned old = atomicAdd(cnt, 1u);
        // counter starts at 0xAAAAAAAA (ws poison) or 0 — accept either
        if (old == (0xAAAAAAAAu + (unsigned)(NCHUNK - 1)) ||
            old == (unsigned)(NCHUNK - 1)) {
            const double xx = atomicAdd(&acc[0], 0.0);  // coherent reads
            const double xy = atomicAdd(&acc[1], 0.0);
            const double yy = atomicAdd(&acc[2], 0.0);
            out[0] = (float)((xx + yy - xy) *
                             (1.0 / ((double)N_HALF * (double)N_HALF)));
        }
    }
}

extern "C" void kernel_launch(void* const* d_in, const int* in_sizes, int n_in,
                              void* d_out, int out_size, void* d_ws, size_t ws_size,
                              hipStream_t stream) {
    const float* X = (const float*)d_in[0];
    const float* Y = (const float*)d_in[1];
    char* ws = (char*)d_ws;
    float* sq        = (float*)ws;               // 8192 f32  [0, 32768)
    float* colsum_r  = (float*)(ws + 32768);     // 8*256 f32 [32768, 40960)
    float* Ssum_r    = (float*)(ws + 40960);     // 8 f32     [40960, 40992)
    unsigned* cnt    = (unsigned*)(ws + 40992);  // 1 u32
    double* acc      = (double*)(ws + 41000);    // 3 f64 (8-aligned)
    float* c2ws      = (float*)(ws + 41024);     // 1 f32
    float* out = (float*)d_out;

    hipLaunchKernelGGL(k_prep, dim3(512), dim3(256), 0, stream,
                       X, Y, sq, colsum_r, Ssum_r);
    hipLaunchKernelGGL(k_bw, dim3(1), dim3(256), 0, stream,
                       colsum_r, Ssum_r, c2ws);
    hipLaunchKernelGGL(k_gram, dim3(NCHUNK), dim3(256), 0, stream,
                       sq, c2ws, acc, cnt, out);
}

// Round 8
// 111.531 us; speedup vs baseline: 1.0856x; 1.0383x over previous
//
#include <hip/hip_runtime.h>
#include <math.h>

// MMD loss. Z = concat(X,Y) [8192 x 256] fp32.
// Round 16: R15 invalidated (A-in-regs spilled: VGPR cap 128, WRITE 8.2MB).
//   Base = R13 (48.5us, best). Remaining stall: per-phase SERIAL chain
//   barrier -> ds_read(~120cyc) -> lgkm -> MFMA, lockstepped across waves.
//   Fix: register read-ahead. Phase g: ds_read slice g+1 into spare frag set
//   WHILE MFMA runs on slice g's regs (loaded last phase). lgkmcnt(0) in the
//   phase-top wait drains the reads (free: full phase to complete) and makes
//   the ring-overwrite proof exact. Counted vmcnt tightened one slice:
//   tile0 = 8 everywhere; tiles>=1 = (16,16,16,8,8,8,8,8) [epilogue's 8 sq
//   loads sit in the queue at kkc 0..2]; last tile tail = (...,8,8,4,0,0).
//   Epilogue sq loads pinned after stage stream by a "" memory-clobber asm.
//   +32 VGPR (2nd frag set), est ~185 < 256 budget; WRITE_SIZE = spill canary.
// Math (R5-R15 verified, absmax 0.0): 1-phase bf16 Gram, sq exact fp32;
//   d2 = sq_i + sq_j - 2 z_i.z_j; bandwidth analytic
//   (sum d2 = 2M*S - 2||sum z||^2); K = t+t^2+t^4+t^8+t^16, t=exp(-d2/(4bw));
//   out = (Sxx + Syy - Sxy_both)/n^2, fp64 accumulation.

#define N_HALF 4096
#define DIM 256
#define M_TOT 8192
#define TILE 128
#define NT 64
#define NT_HALF 32
#define NCHUNK 512  // blocks; 480 do 4 tiles, 32 (cc%16==0) do 5: 2080 total

typedef unsigned short ushort_t;
typedef __attribute__((ext_vector_type(8))) short short8;   // 8 bf16 = 4 VGPRs
typedef __attribute__((ext_vector_type(4))) float floatx4;  // MFMA C/D

// Fragment-swizzled bf16 Z (4 MB). For row-block rb (16 rows) and k-chunk kk
// (32 k): g_zf[rb*4096 + kk*512 + q*128 + m*8 + j] = Z[rb*16+m][kk*32+q*8+j].
// The 16B unit of lane (quad=q, l15=m) sits at byte lane*16 within the 1KB
// chunk: MFMA frag ds_read_b128 is linear in lane -> conflict-free; staging
// global_load_lds (dest base+lane*16, src +lane*16) is a pure linear copy.
__device__ ushort_t g_zf[M_TOT * DIM];

__device__ __forceinline__ ushort_t f2bf(float f) {  // RNE, finite inputs
    unsigned u = __float_as_uint(f);
    u += 0x7fffu + ((u >> 16) & 1u);
    return (ushort_t)(u >> 16);
}

__device__ __forceinline__ void gload_lds16(const ushort_t* g, ushort_t* l) {
    __builtin_amdgcn_global_load_lds(
        (const __attribute__((address_space(1))) void*)g,
        (__attribute__((address_space(3))) void*)l, 16, 0, 0);
}

// Stage one kk-slice (A 8KB + B 8KB) into one ring buffer.
// Wave w stages chunks {2w, 2w+1} of A and B: 4 gload_lds of 1KB per wave.
__device__ __forceinline__ void stage1(const ushort_t* gA, const ushort_t* gB,
                                       int kk, ushort_t* buf, int wave, int lane) {
#pragma unroll
    for (int i = 0; i < 2; ++i) {
        const int c = wave * 2 + i;
        gload_lds16(gA + (size_t)c * 4096 + kk * 512 + lane * 8, buf + c * 512);
        gload_lds16(gB + (size_t)c * 4096 + kk * 512 + lane * 8, buf + 4096 + c * 512);
    }
}

// ---------------- k_prep: convert(swizzled) + row norms + col sums -----------
// 512 blocks x 256 threads; wave w owns 4 rows; lane l owns cols [4l,4l+4).
__global__ __launch_bounds__(256) void k_prep(const float* __restrict__ X,
                                              const float* __restrict__ Y,
                                              float* __restrict__ sq,
                                              float* __restrict__ colsum_r,
                                              float* __restrict__ Ssum_r) {
    __shared__ float cpart[4][256];
    __shared__ float spart[4];
    const int t = threadIdx.x, wave = t >> 6, lane = t & 63;
    const int row0 = blockIdx.x * 16 + wave * 4;
    // swizzle coords for this lane's 4 columns [4l, 4l+4)
    const int kk = lane >> 3, q = (lane >> 1) & 3, j0 = (lane & 1) * 4;
    float c0 = 0.f, c1 = 0.f, c2 = 0.f, c3 = 0.f, ssum = 0.f;
#pragma unroll
    for (int i = 0; i < 4; ++i) {
        const int row = row0 + i;
        const float* p = (row < N_HALF) ? (X + (size_t)row * DIM)
                                        : (Y + (size_t)(row - N_HALF) * DIM);
        const float4 v = *((const float4*)p + lane);
        ushort4 hi;
        hi.x = f2bf(v.x); hi.y = f2bf(v.y); hi.z = f2bf(v.z); hi.w = f2bf(v.w);
        const int rb = row >> 4, m = row & 15;
        *(ushort4*)(g_zf + (size_t)rb * 4096 + kk * 512 + q * 128 + m * 8 + j0) = hi;
        c0 += v.x; c1 += v.y; c2 += v.z; c3 += v.w;
        float s = fmaf(v.x, v.x, fmaf(v.y, v.y, fmaf(v.z, v.z, v.w * v.w)));
#pragma unroll
        for (int off = 32; off > 0; off >>= 1) s += __shfl_xor(s, off);
        if (lane == 0) sq[row] = s;
        ssum += s;  // butterfly left full sum in every lane
    }
    float4 cp; cp.x = c0; cp.y = c1; cp.z = c2; cp.w = c3;
    *(float4*)&cpart[wave][lane * 4] = cp;
    if (lane == 0) spart[wave] = ssum;
    __syncthreads();
    const float cs = cpart[0][t] + cpart[1][t] + cpart[2][t] + cpart[3][t];
    const int rep = blockIdx.x & 7;  // 8 replicas -> 64 adds/address
    atomicAdd(&colsum_r[rep * 256 + t], cs);  // poison -3e-13/rep: harmless
    if (t == 0) atomicAdd(&Ssum_r[rep], spart[0] + spart[1] + spart[2] + spart[3]);
}

// ---------------- k_bw: one block computes exp2 scale c2 once ----------------
// Same summation order as the old per-block prologue -> bit-identical c2.
__global__ __launch_bounds__(256) void k_bw(const float* __restrict__ colsum_r,
                                            const float* __restrict__ Ssum_r,
                                            float* __restrict__ c2out) {
    __shared__ double sred[4];
    const int t = threadIdx.x, lane = t & 63, wave = t >> 6;
    float csf = 0.f;
#pragma unroll
    for (int r = 0; r < 8; ++r) csf += colsum_r[r * 256 + t];
    double p = (double)csf * (double)csf;
#pragma unroll
    for (int off = 32; off > 0; off >>= 1) p += __shfl_xor(p, off);
    if (lane == 0) sred[wave] = p;
    __syncthreads();
    if (t == 0) {
        const double SS = sred[0] + sred[1] + sred[2] + sred[3];
        float Sf = 0.f;
#pragma unroll
        for (int r = 0; r < 8; ++r) Sf += Ssum_r[r];
        const double sum_d2 = 2.0 * (double)M_TOT * (double)Sf - 2.0 * SS;
        const double bw = sum_d2 / ((double)M_TOT * (double)M_TOT - (double)M_TOT);
        c2out[0] = (float)(1.4426950408889634 / (4.0 * bw));  // exp2 scale
    }
}

// ---------------- k_gram: read-ahead + counted-vmcnt ring MFMA Gram ----------
// 512 blocks x 256 threads = 2 blocks/CU; 4x16KB LDS ring; frag regs
// double-buffered so ds_read(g+1) overlaps MFMA(g) inside each phase.
__global__ __launch_bounds__(256, 2) void k_gram(const float* __restrict__ sq,
                                                 const float* __restrict__ c2p,
                                                 double* __restrict__ acc,
                                                 unsigned* __restrict__ cnt,
                                                 float* __restrict__ out) {
    // ring buf b: A slice [0,4096), B slice [4096,8192) ushorts (8 KB each).
    __shared__ __attribute__((aligned(16))) ushort_t lds[4][8192];
    __shared__ double redw[4][3];

    // XCD-band swizzle (512 = 8*64): same-XCD blocks contiguous in triangle.
    const int bid = (int)blockIdx.x;
    const int cc = (bid & 7) * 64 + (bid >> 3);
    // 32 long blocks (cc%16==0 -> 4 per XCD) do 5 tiles; rest do 4.
    const int nst = ((cc & 15) == 0) ? 5 : 4;
    const int f0 = cc * 4 + ((cc + 15) >> 4);  // first flat tile of this block

    const int t = threadIdx.x;
    const int lane = t & 63, wave = t >> 6;
    const int l15 = lane & 15, quad = lane >> 4;
    const int wrow = (wave >> 1) * 64, wcol = (wave & 1) * 64;
    const int a0 = (wave >> 1) * 4, b0 = (wave & 1) * 4;  // frag chunk bases
    const int laneoff = quad * 128 + l15 * 8;  // = lane*16B: linear, no conflict

    const float c2 = c2p[0];  // wave-uniform scalar load
    const float twoc2 = 2.f * c2;

    // triangular decode of f0 -> (ti, tj), tj >= ti
    int ti = (int)((129.0f - sqrtf(16641.0f - 8.0f * (float)f0)) * 0.5f);
    if (ti < 0) ti = 0; if (ti > NT - 1) ti = NT - 1;
    while (ti * NT - ti * (ti - 1) / 2 > f0) --ti;
    while ((ti + 1) * NT - (ti + 1) * ti / 2 <= f0) ++ti;
    int tj = ti + (f0 - (ti * NT - ti * (ti - 1) / 2));

    // stage stream (runs 4 slices ahead of compute issue point)
    int s_ti = ti, s_tj = tj, s_kk = 0;
    const ushort_t* sgA = g_zf + (size_t)s_ti * 32768;
    const ushort_t* sgB = g_zf + (size_t)s_tj * 32768;
#define ADV_STAGE() do { if (++s_kk == 8) { s_kk = 0; ++s_tj;                 \
        if (s_tj == NT) { ++s_ti; s_tj = s_ti; }                              \
        sgA = g_zf + (size_t)s_ti * 32768;                                    \
        sgB = g_zf + (size_t)s_tj * 32768; } } while (0)

    // prime slices 0..3 into bufs 0..3 (16 loads in flight per wave)
#pragma unroll
    for (int p = 0; p < 4; ++p) {
        stage1(sgA, sgB, s_kk, lds[p], wave, lane);
        ADV_STAGE();
    }
    asm volatile("s_waitcnt vmcnt(12)" ::: "memory");  // slice 0 retired
    __builtin_amdgcn_s_barrier();
    __builtin_amdgcn_sched_barrier(0);

    // fragment register double-buffer; prologue read of slice 0 -> set 0
    short8 af0[4], bf0[4], af1[4], bf1[4];
#pragma unroll
    for (int mi = 0; mi < 4; ++mi)
        af0[mi] = *(const short8*)(lds[0] + (a0 + mi) * 512 + laneoff);
#pragma unroll
    for (int ni = 0; ni < 4; ++ni)
        bf0[ni] = *(const short8*)(lds[0] + 4096 + (b0 + ni) * 512 + laneoff);

    double lxx = 0.0, lxy = 0.0, lyy = 0.0;

#pragma unroll 1
    for (int s = 0; s < nst; ++s) {
        const bool lastT = (s == nst - 1);
        const bool firstT = (s == 0);

        floatx4 accv[4][4];
#pragma unroll
        for (int mi = 0; mi < 4; ++mi)
#pragma unroll
            for (int ni = 0; ni < 4; ++ni) accv[mi][ni] = (floatx4)0.f;

#pragma unroll
        for (int kkc = 0; kkc < 8; ++kkc) {
            // top-of-phase: counted vmcnt (retire slice g+1, about to ds_read)
            // + lgkmcnt(0) (drain last phase's ds_reads -> overwrite-safe).
            // Queue per wave: slices = 4 loads, epilogue sq batch = 8 loads
            // (sits in queue at kkc 0..2 of tiles >= 1). Verified in-order.
            if (lastT && kkc == 5)
                asm volatile("s_waitcnt vmcnt(4) lgkmcnt(0)" ::: "memory");
            else if (lastT && kkc >= 6)
                asm volatile("s_waitcnt vmcnt(0) lgkmcnt(0)" ::: "memory");
            else if (!firstT && kkc <= 2)
                asm volatile("s_waitcnt vmcnt(16) lgkmcnt(0)" ::: "memory");
            else
                asm volatile("s_waitcnt vmcnt(8) lgkmcnt(0)" ::: "memory");
            __builtin_amdgcn_s_barrier();
            __builtin_amdgcn_sched_barrier(0);

            // read-ahead: slice g+1 from buf (g+1)&3 into the spare reg set;
            // completes under this phase's MFMA.
            if (!(lastT && kkc == 7)) {
                const ushort_t* nA = lds[(kkc + 1) & 3];
                const ushort_t* nB = nA + 4096;
                if ((kkc & 1) == 0) {
#pragma unroll
                    for (int mi = 0; mi < 4; ++mi)
                        af1[mi] = *(const short8*)(nA + (a0 + mi) * 512 + laneoff);
#pragma unroll
                    for (int ni = 0; ni < 4; ++ni)
                        bf1[ni] = *(const short8*)(nB + (b0 + ni) * 512 + laneoff);
                } else {
#pragma unroll
                    for (int mi = 0; mi < 4; ++mi)
                        af0[mi] = *(const short8*)(nA + (a0 + mi) * 512 + laneoff);
#pragma unroll
                    for (int ni = 0; ni < 4; ++ni)
                        bf0[ni] = *(const short8*)(nB + (b0 + ni) * 512 + laneoff);
                }
            }

            // stage slice g+4 into buf (g+4)&3 == kkc&3 (its last readers
            // drained at this phase's lgkmcnt(0)+barrier).
            if (!lastT || kkc <= 3) {
                stage1(sgA, sgB, s_kk, lds[kkc & 3], wave, lane);
                ADV_STAGE();
            }

            // MFMA on the set loaded LAST phase (no lgkm wait needed).
            __builtin_amdgcn_s_setprio(1);
            if ((kkc & 1) == 0) {
#pragma unroll
                for (int mi = 0; mi < 4; ++mi)
#pragma unroll
                    for (int ni = 0; ni < 4; ++ni)
                        accv[mi][ni] = __builtin_amdgcn_mfma_f32_16x16x32_bf16(
                            af0[mi], bf0[ni], accv[mi][ni], 0, 0, 0);
            } else {
#pragma unroll
                for (int mi = 0; mi < 4; ++mi)
#pragma unroll
                    for (int ni = 0; ni < 4; ++ni)
                        accv[mi][ni] = __builtin_amdgcn_mfma_f32_16x16x32_bf16(
                            af1[mi], bf1[ni], accv[mi][ni], 0, 0, 0);
            }
            __builtin_amdgcn_s_setprio(0);
        }

        // pin the epilogue's sq loads AFTER all stage issues (vm-queue order
        // is what the counted vmcnt schedule above assumes).
        asm volatile("" ::: "memory");

        // ---- epilogue for (ti, tj). C/D: col = lane&15, row = quad*4+reg.
        const int arow0 = ti * TILE, brow0 = tj * TILE;
        float nsj[4];
#pragma unroll
        for (int ni = 0; ni < 4; ++ni)
            nsj[ni] = -c2 * sq[brow0 + wcol + ni * 16 + l15];
        floatx4 nsi4[4];
#pragma unroll
        for (int mi = 0; mi < 4; ++mi) {
            const float4 sv = *(const float4*)&sq[arow0 + wrow + mi * 16 + quad * 4];
            nsi4[mi][0] = -c2 * sv.x; nsi4[mi][1] = -c2 * sv.y;
            nsi4[mi][2] = -c2 * sv.z; nsi4[mi][3] = -c2 * sv.w;
        }
        floatx4 sum4 = (floatx4)0.f;
#pragma unroll
        for (int mi = 0; mi < 4; ++mi) {
#pragma unroll
            for (int ni = 0; ni < 4; ++ni) {
                const floatx4 addv = nsi4[mi] + (floatx4)nsj[ni];
                floatx4 arg = twoc2 * accv[mi][ni] + addv;
                floatx4 tt;
#pragma unroll
                for (int r = 0; r < 4; ++r) tt[r] = exp2f(fminf(arg[r], 0.f));
                const floatx4 t2 = tt * tt, t4 = t2 * t2, t8 = t4 * t4, t16 = t8 * t8;
                sum4 += (tt + t2) + (t4 + t8) + t16;
            }
        }
        const float fsum = (sum4[0] + sum4[1]) + (sum4[2] + sum4[3]);
        const double contrib = ((ti == tj) ? 1.0 : 2.0) * (double)fsum;
        if (tj < NT_HALF)       lxx += contrib;   // block-uniform branches
        else if (ti < NT_HALF)  lxy += contrib;
        else                    lyy += contrib;

        // advance compute tile
        ++tj; if (tj == NT) { ++ti; tj = ti; }
    }
#undef ADV_STAGE

    // ---- block reduction + finalize ----
#pragma unroll
    for (int off = 32; off > 0; off >>= 1) {
        lxx += __shfl_xor(lxx, off);
        lxy += __shfl_xor(lxy, off);
        lyy += __shfl_xor(lyy, off);
    }
    if (lane == 0) { redw[wave][0] = lxx; redw[wave][1] = lxy; redw[wave][2] = lyy; }
    __syncthreads();
    if (t == 0) {
        double sxx = 0.0, sxy = 0.0, syy = 0.0;
#pragma unroll
        for (int wv = 0; wv < 4; ++wv) {
            sxx += redw[wv][0]; sxy += redw[wv][1]; syy += redw[wv][2];
        }
        if (sxx != 0.0) atomicAdd(&acc[0], sxx);
        if (sxy != 0.0) atomicAdd(&acc[1], sxy);
        if (syy != 0.0) atomicAdd(&acc[2], syy);
        __threadfence();  // release region adds before counter bump
        const unsigned old = atomicAdd(cnt, 1u);
        // counter starts at 0xAAAAAAAA (ws poison) or 0 — accept either
        if (old == (0xAAAAAAAAu + (unsigned)(NCHUNK - 1)) ||
            old == (unsigned)(NCHUNK - 1)) {
            const double xx = atomicAdd(&acc[0], 0.0);  // coherent reads
            const double xy = atomicAdd(&acc[1], 0.0);
            const double yy = atomicAdd(&acc[2], 0.0);
            out[0] = (float)((xx + yy - xy) *
                             (1.0 / ((double)N_HALF * (double)N_HALF)));
        }
    }
}

extern "C" void kernel_launch(void* const* d_in, const int* in_sizes, int n_in,
                              void* d_out, int out_size, void* d_ws, size_t ws_size,
                              hipStream_t stream) {
    const float* X = (const float*)d_in[0];
    const float* Y = (const float*)d_in[1];
    char* ws = (char*)d_ws;
    float* sq        = (float*)ws;               // 8192 f32  [0, 32768)
    float* colsum_r  = (float*)(ws + 32768);     // 8*256 f32 [32768, 40960)
    float* Ssum_r    = (float*)(ws + 40960);     // 8 f32     [40960, 40992)
    unsigned* cnt    = (unsigned*)(ws + 40992);  // 1 u32
    double* acc      = (double*)(ws + 41000);    // 3 f64 (8-aligned)
    float* c2ws      = (float*)(ws + 41024);     // 1 f32
    float* out = (float*)d_out;

    hipLaunchKernelGGL(k_prep, dim3(512), dim3(256), 0, stream,
                       X, Y, sq, colsum_r, Ssum_r);
    hipLaunchKernelGGL(k_bw, dim3(1), dim3(256), 0, stream,
                       colsum_r, Ssum_r, c2ws);
    hipLaunchKernelGGL(k_gram, dim3(NCHUNK), dim3(256), 0, stream,
                       sq, c2ws, acc, cnt, out);
}